// Round 1
// baseline (318.751 us; speedup 1.0000x reference)
//
#include <hip/hip_runtime.h>
#include <math.h>

#define HID 50
#define NPTS 8192
#define NPARA 5000
#define NLAYERS 4

// LDS arrays padded so lanes 50..63 read in-bounds (values never used: masked
// or never broadcast from lanes >= 50).
#define SWIN_SZ (3*HID + 16)      // max idx 2*50+63 = 163
#define SBIN_SZ (HID + 16)        // max idx 63
#define SWH_SZ  (NLAYERS*HID*HID + 16) // max idx 3*2500+49*50+63 = 10013
#define SBH_SZ  (NLAYERS*HID + 16)     // max idx 3*50+63 = 213
#define SWO_SZ  (2*64)            // max idx 63*2+1 = 127

__global__ __launch_bounds__(256) void point_kernel(
    const float* __restrict__ x,
    const float* __restrict__ W_in, const float* __restrict__ b_in,
    const float* __restrict__ W_hid, const float* __restrict__ b_hid,
    const float* __restrict__ W_out, const float* __restrict__ b_out,
    double* __restrict__ sums)
{
    __shared__ float sWin[SWIN_SZ];
    __shared__ float sbin[SBIN_SZ];
    __shared__ float sWh[SWH_SZ];
    __shared__ float sbh[SBH_SZ];
    __shared__ float sWo[SWO_SZ];
    __shared__ float sbo[2];

    const int tid = threadIdx.x;
    for (int i = tid; i < 3*HID; i += 256) sWin[i] = W_in[i];
    for (int i = 3*HID + tid; i < SWIN_SZ; i += 256) sWin[i] = 0.f;
    for (int i = tid; i < HID; i += 256) sbin[i] = b_in[i];
    for (int i = HID + tid; i < SBIN_SZ; i += 256) sbin[i] = 0.f;
    for (int i = tid; i < NLAYERS*HID*HID; i += 256) sWh[i] = W_hid[i];
    for (int i = NLAYERS*HID*HID + tid; i < SWH_SZ; i += 256) sWh[i] = 0.f;
    for (int i = tid; i < NLAYERS*HID; i += 256) sbh[i] = b_hid[i];
    for (int i = NLAYERS*HID + tid; i < SBH_SZ; i += 256) sbh[i] = 0.f;
    for (int i = tid; i < 2*HID; i += 256) sWo[i] = W_out[i];
    for (int i = 2*HID + tid; i < SWO_SZ; i += 256) sWo[i] = 0.f;
    if (tid < 2) sbo[tid] = b_out[tid];
    __syncthreads();

    const int lane  = tid & 63;
    const int wave  = tid >> 6;
    const int gwave = blockIdx.x * 4 + wave;
    const int nwave = gridDim.x * 4;

    double a0 = 0.0, a1 = 0.0, a2 = 0.0, a3 = 0.0, a4 = 0.0, a5 = 0.0;

    for (int p = gwave; p < NPTS; p += nwave) {
        const float x0 = x[3*p+0], x1 = x[3*p+1], x2 = x[3*p+2];

        // ---- input layer: z = x @ W_in + b_in ----
        const float w0 = sWin[lane];
        const float w1 = sWin[HID + lane];
        const float w2 = sWin[2*HID + lane];
        float z = fmaf(x0, w0, fmaf(x1, w1, fmaf(x2, w2, sbin[lane])));
        float h = tanhf(z);
        float s = 1.f - h*h;
        float hx = s*w0, hy = s*w1, ht = s*w2;
        float hxx = -2.f*h*s*w0*w0;
        float hyy = -2.f*h*s*w1*w1;

        // ---- hidden layers ----
        for (int l = 0; l < NLAYERS; ++l) {
            const float* Wl = &sWh[l*HID*HID];
            float za  = sbh[l*HID + lane];
            float zx = 0.f, zy = 0.f, zt = 0.f, zxx = 0.f, zyy = 0.f;
            #pragma unroll
            for (int k = 0; k < HID; ++k) {
                const float w = Wl[k*HID + lane];
                za  = fmaf(__shfl(h,   k), w, za);
                zx  = fmaf(__shfl(hx,  k), w, zx);
                zy  = fmaf(__shfl(hy,  k), w, zy);
                zt  = fmaf(__shfl(ht,  k), w, zt);
                zxx = fmaf(__shfl(hxx, k), w, zxx);
                zyy = fmaf(__shfl(hyy, k), w, zyy);
            }
            const float hn = tanhf(za);
            const float sn = 1.f - hn*hn;
            hxx = fmaf(sn, zxx, -2.f*hn*sn*zx*zx);
            hyy = fmaf(sn, zyy, -2.f*hn*sn*zy*zy);
            hx = sn*zx; hy = sn*zy; ht = sn*zt;
            h = hn;
        }

        // ---- output layer partials + wave reduction ----
        const float wo0 = sWo[lane*2+0];
        const float wo1 = sWo[lane*2+1];
        const bool act = (lane < HID);
        float pu   = act ? h  *wo0 : 0.f;
        float pv   = act ? h  *wo1 : 0.f;
        float put  = act ? ht *wo0 : 0.f;
        float pvt  = act ? ht *wo1 : 0.f;
        float puxx = act ? hxx*wo0 : 0.f;
        float pvxx = act ? hxx*wo1 : 0.f;
        float puyy = act ? hyy*wo0 : 0.f;
        float pvyy = act ? hyy*wo1 : 0.f;
        #pragma unroll
        for (int off = 32; off > 0; off >>= 1) {
            pu   += __shfl_xor(pu,   off);
            pv   += __shfl_xor(pv,   off);
            put  += __shfl_xor(put,  off);
            pvt  += __shfl_xor(pvt,  off);
            puxx += __shfl_xor(puxx, off);
            pvxx += __shfl_xor(pvxx, off);
            puyy += __shfl_xor(puyy, off);
            pvyy += __shfl_xor(pvyy, off);
        }
        const float u = pu + sbo[0];
        const float v = pv + sbo[1];
        const float Q = u*u + v*v;
        // base1 = v_t - 0.5 u_xx - 0.5 v_yy - Q u + v
        const float g1 = pvt - 0.5f*puxx - 0.5f*pvyy - Q*u + v;
        // base2 = u_t + 0.5 v_xx - 0.5 u_yy + Q v + u
        const float g2 = put + 0.5f*pvxx - 0.5f*puyy + Q*v + u;
        const float h1 = 0.5f*puyy, h2 = 0.5f*pvyy;
        const float k1 = Q*v,       k2 = Q*u;

        // f1 = g1 - a*h1 - cc*k1 ; f2 = g2 + a*h2 - cc*k2
        // mean(f1^2)+mean(f2^2) = (S0 + a^2 S1 + cc^2 S2 + 2a S3 - 2cc S4 + 2a cc S5)/N
        a0 += (double)g1*(double)g1 + (double)g2*(double)g2;
        a1 += (double)h1*(double)h1 + (double)h2*(double)h2;
        a2 += (double)k1*(double)k1 + (double)k2*(double)k2;
        a3 += (double)g2*(double)h2 - (double)g1*(double)h1;
        a4 += (double)g1*(double)k1 + (double)g2*(double)k2;
        a5 += (double)h1*(double)k1 - (double)h2*(double)k2;
    }

    if (lane == 0) {
        atomicAdd(&sums[0], a0);
        atomicAdd(&sums[1], a1);
        atomicAdd(&sums[2], a2);
        atomicAdd(&sums[3], a3);
        atomicAdd(&sums[4], a4);
        atomicAdd(&sums[5], a5);
    }
}

__global__ __launch_bounds__(256) void para_kernel(
    const float* __restrict__ para,
    const double* __restrict__ sums,
    float* __restrict__ out)
{
    const int p = blockIdx.x * 256 + threadIdx.x;
    if (p >= NPARA) return;
    const double a  = (double)para[3*p+0];
    const double cc = (double)para[3*p+2];
    const double r = sums[0]
                   + a*a*sums[1]
                   + cc*cc*sums[2]
                   + 2.0*a*sums[3]
                   - 2.0*cc*sums[4]
                   + 2.0*a*cc*sums[5];
    out[p] = (float)(r * (1.0 / (double)NPTS));
}

extern "C" void kernel_launch(void* const* d_in, const int* in_sizes, int n_in,
                              void* d_out, int out_size, void* d_ws, size_t ws_size,
                              hipStream_t stream) {
    const float* x     = (const float*)d_in[0];
    const float* para  = (const float*)d_in[1];
    const float* W_in  = (const float*)d_in[2];
    const float* b_in  = (const float*)d_in[3];
    const float* W_hid = (const float*)d_in[4];
    const float* b_hid = (const float*)d_in[5];
    const float* W_out = (const float*)d_in[6];
    const float* b_out = (const float*)d_in[7];
    double* sums = (double*)d_ws;

    hipMemsetAsync(sums, 0, 6*sizeof(double), stream);
    point_kernel<<<512, 256, 0, stream>>>(x, W_in, b_in, W_hid, b_hid,
                                          W_out, b_out, sums);
    para_kernel<<<(NPARA + 255)/256, 256, 0, stream>>>(para, sums, (float*)d_out);
}